// Round 2
// baseline (235.942 us; speedup 1.0000x reference)
//
#include <hip/hip_runtime.h>
#include <hip/hip_fp16.h>

// SSM = batched cosine self-similarity.  pianoroll [8,2048,512] f32 -> ssm [8,2048,2048] f32.
// Pass 1: row-normalize -> f16 in d_ws.
// Pass 2: C[b] = Xn Xn^T, exploiting symmetry: only lower-triangle 128x128 tile
//         pairs are computed (136/batch vs 256); off-diagonal blocks write the
//         tile AND its mirror (transposed through LDS for coalesced stores).

typedef _Float16 half8 __attribute__((ext_vector_type(8)));
typedef float floatx4 __attribute__((ext_vector_type(4)));

#define B_    8
#define T_    2048
#define D_    512

#define GLOAD_LDS16(g, l)                                                   \
    __builtin_amdgcn_global_load_lds(                                       \
        (const __attribute__((address_space(1))) void*)(g),                 \
        (__attribute__((address_space(3))) void*)(l), 16, 0, 0)

// ---------------------------------------------------------------------------
__global__ __launch_bounds__(256) void normalize_f16(
        const float* __restrict__ x, _Float16* __restrict__ xn) {
    const int row  = blockIdx.x * 4 + (threadIdx.x >> 6);
    const int lane = threadIdx.x & 63;
    const size_t base = (size_t)row * D_ + lane * 8;

    const float4* p = (const float4*)(x + base);
    float4 v0 = p[0];
    float4 v1 = p[1];
    float s = v0.x * v0.x + v0.y * v0.y + v0.z * v0.z + v0.w * v0.w
            + v1.x * v1.x + v1.y * v1.y + v1.z * v1.z + v1.w * v1.w;
    #pragma unroll
    for (int off = 32; off > 0; off >>= 1) s += __shfl_xor(s, off);

    const float sc = 1.0f / fmaxf(sqrtf(s), 1e-12f);
    half8 h;
    h[0] = (_Float16)(v0.x * sc);
    h[1] = (_Float16)(v0.y * sc);
    h[2] = (_Float16)(v0.z * sc);
    h[3] = (_Float16)(v0.w * sc);
    h[4] = (_Float16)(v1.x * sc);
    h[5] = (_Float16)(v1.y * sc);
    h[6] = (_Float16)(v1.z * sc);
    h[7] = (_Float16)(v1.w * sc);
    *(half8*)(xn + base) = h;
}

// ---------------------------------------------------------------------------
// Grid (136, 8), block 256 (4 waves). Pair p -> (bi,bj), bi>=bj.
// LDS: staging 2x(128x32 f16)=16KB, reused after K-loop as 4x(64x20 f32)=20KB
// per-wave transpose buffers (stride 20 floats: 16B-aligned for b128, spreads
// banks). Epilogue: normal tile scalar stores (64B segments); off-diag blocks
// additionally transpose each wave's 64x64 quadrant in 16-row bands and store
// the mirror tile as float4 rows.
// ---------------------------------------------------------------------------
union SMem {
    struct { _Float16 a[128 * 32]; _Float16 b[128 * 32]; } st; // 16 KB
    float tr[4][64 * 20];                                      // 20 KB
};

__global__ __launch_bounds__(256) void ssm_gemm(
        const _Float16* __restrict__ xn, float* __restrict__ out) {
    __shared__ SMem sm;

    // decode lower-triangle pair index
    const int p = blockIdx.x;
    int bi = (int)((sqrtf(8.0f * (float)p + 1.0f) - 1.0f) * 0.5f);
    while ((bi + 1) * (bi + 2) / 2 <= p) ++bi;
    while (bi * (bi + 1) / 2 > p) --bi;
    const int bj = p - bi * (bi + 1) / 2;

    const int m0 = bi * 128;   // row tile
    const int n0 = bj * 128;   // col tile
    const _Float16* __restrict__ Xb = xn + (size_t)blockIdx.y * T_ * D_;
    float* __restrict__ Cb = out + (size_t)blockIdx.y * T_ * T_;

    const int tid  = threadIdx.x;
    const int wave = tid >> 6;
    const int lane = tid & 63;
    const int wrow = (wave >> 1) * 64;
    const int wcol = (wave & 1) * 64;

    const int srow = wave * 32 + (lane >> 2);
    const _Float16* ga = Xb + (size_t)(m0 + srow) * D_ + (lane & 3) * 8;
    const _Float16* gb = Xb + (size_t)(n0 + srow) * D_ + (lane & 3) * 8;
    _Float16* la = sm.st.a + wave * 1024;
    _Float16* lb = sm.st.b + wave * 1024;

    const int fr = lane & 15;
    const int fk = (lane >> 4) * 8;

    floatx4 acc[4][4] = {};

    for (int k0 = 0; k0 < D_; k0 += 32) {
        GLOAD_LDS16(ga + k0,           la);
        GLOAD_LDS16(ga + k0 + 16 * D_, la + 512);
        GLOAD_LDS16(gb + k0,           lb);
        GLOAD_LDS16(gb + k0 + 16 * D_, lb + 512);
        __syncthreads();

        half8 af[4], bf[4];
        #pragma unroll
        for (int i = 0; i < 4; ++i) {
            af[i] = *(const half8*)(sm.st.a + (wrow + i * 16 + fr) * 32 + fk);
            bf[i] = *(const half8*)(sm.st.b + (wcol + i * 16 + fr) * 32 + fk);
        }
        #pragma unroll
        for (int i = 0; i < 4; ++i)
            #pragma unroll
            for (int j = 0; j < 4; ++j)
                acc[i][j] = __builtin_amdgcn_mfma_f32_16x16x32_f16(
                    af[i], bf[j], acc[i][j], 0, 0, 0);
        __syncthreads();
    }

    // ---- normal tile: C/D layout col=lane&15, row=(lane>>4)*4+reg ----
    const int crow = m0 + wrow + (lane >> 4) * 4;
    const int ccol = n0 + wcol + (lane & 15);
    #pragma unroll
    for (int i = 0; i < 4; ++i)
        #pragma unroll
        for (int j = 0; j < 4; ++j)
            #pragma unroll
            for (int r = 0; r < 4; ++r)
                Cb[(size_t)(crow + i * 16 + r) * T_ + (ccol + j * 16)] = acc[i][j][r];

    if (bi == bj) return;   // block-uniform branch; diagonal done

    // ---- mirror tile via per-wave LDS transpose, 16-row bands ----
    float* reg = sm.tr[wave];
    const int rl = (lane >> 4) * 4;          // row_local base (0,4,8,12)
    #pragma unroll
    for (int i = 0; i < 4; ++i) {
        // scatter band i (rows wrow+i*16..+16, cols wcol..+64) as [col][row]
        #pragma unroll
        for (int j = 0; j < 4; ++j)
            #pragma unroll
            for (int r = 0; r < 4; ++r)
                reg[(j * 16 + (lane & 15)) * 20 + rl + r] = acc[i][j][r];
        __syncthreads();
        // gather transposed: lane = mirror row offset (orig col), 4x float4
        const size_t mrow = (size_t)(n0 + wcol + lane) * T_ + m0 + wrow + i * 16;
        #pragma unroll
        for (int q = 0; q < 4; ++q) {
            floatx4 v = *(const floatx4*)(reg + lane * 20 + q * 4);
            *(floatx4*)(Cb + mrow + q * 4) = v;
        }
        __syncthreads();
    }
}

extern "C" void kernel_launch(void* const* d_in, const int* in_sizes, int n_in,
                              void* d_out, int out_size, void* d_ws, size_t ws_size,
                              hipStream_t stream) {
    const float* x = (const float*)d_in[0];
    float* out = (float*)d_out;
    _Float16* xn = (_Float16*)d_ws;   // 8*2048*512 f16 = 16.8 MB

    normalize_f16<<<dim3(B_ * T_ / 4), dim3(256), 0, stream>>>(x, xn);
    ssm_gemm<<<dim3(136, B_), dim3(256), 0, stream>>>(xn, out);
}

// Round 3
// 185.026 us; speedup vs baseline: 1.2752x; 1.2752x over previous
//
#include <hip/hip_runtime.h>
#include <hip/hip_fp16.h>

// SSM = batched cosine self-similarity.  pianoroll [8,2048,512] f32 -> ssm [8,2048,2048] f32.
// Pass 1: row-normalize -> f16 in d_ws.
// Pass 2: C[b] = Xn Xn^T, symmetric: only lower-triangle 128x128 tile pairs
//         (136/batch). Off-diagonal blocks write the tile AND its mirror.
//         Mirror is stored DIRECTLY from the accumulator with swapped row/col
//         indexing (scattered 4B stores; L2 write-back merges lines) — the R2
//         LDS-transpose epilogue had an 8-way-conflict scatter (stride 20,
//         3.27e7 conflict cycles) + 8 barriers and cost ~40 us.

typedef _Float16 half8 __attribute__((ext_vector_type(8)));
typedef float floatx4 __attribute__((ext_vector_type(4)));

#define B_    8
#define T_    2048
#define D_    512

#define GLOAD_LDS16(g, l)                                                   \
    __builtin_amdgcn_global_load_lds(                                       \
        (const __attribute__((address_space(1))) void*)(g),                 \
        (__attribute__((address_space(3))) void*)(l), 16, 0, 0)

// ---------------------------------------------------------------------------
__global__ __launch_bounds__(256) void normalize_f16(
        const float* __restrict__ x, _Float16* __restrict__ xn) {
    const int row  = blockIdx.x * 4 + (threadIdx.x >> 6);
    const int lane = threadIdx.x & 63;
    const size_t base = (size_t)row * D_ + lane * 8;

    const float4* p = (const float4*)(x + base);
    float4 v0 = p[0];
    float4 v1 = p[1];
    float s = v0.x * v0.x + v0.y * v0.y + v0.z * v0.z + v0.w * v0.w
            + v1.x * v1.x + v1.y * v1.y + v1.z * v1.z + v1.w * v1.w;
    #pragma unroll
    for (int off = 32; off > 0; off >>= 1) s += __shfl_xor(s, off);

    const float sc = 1.0f / fmaxf(sqrtf(s), 1e-12f);
    half8 h;
    h[0] = (_Float16)(v0.x * sc);
    h[1] = (_Float16)(v0.y * sc);
    h[2] = (_Float16)(v0.z * sc);
    h[3] = (_Float16)(v0.w * sc);
    h[4] = (_Float16)(v1.x * sc);
    h[5] = (_Float16)(v1.y * sc);
    h[6] = (_Float16)(v1.z * sc);
    h[7] = (_Float16)(v1.w * sc);
    *(half8*)(xn + base) = h;
}

// ---------------------------------------------------------------------------
// Grid (136, 8), block 256 (4 waves). Pair p -> (bi,bj), bi>=bj.
// LDS: 2 x (128 rows x 32 halves) staging, 16 KB. K-loop: 512/32 = 16 iters.
// ---------------------------------------------------------------------------
__global__ __launch_bounds__(256) void ssm_gemm(
        const _Float16* __restrict__ xn, float* __restrict__ out) {
    __shared__ _Float16 ldsA[128 * 32];
    __shared__ _Float16 ldsB[128 * 32];

    // decode lower-triangle pair index
    const int p = blockIdx.x;
    int bi = (int)((sqrtf(8.0f * (float)p + 1.0f) - 1.0f) * 0.5f);
    while ((bi + 1) * (bi + 2) / 2 <= p) ++bi;
    while (bi * (bi + 1) / 2 > p) --bi;
    const int bj = p - bi * (bi + 1) / 2;

    const int m0 = bi * 128;   // row tile
    const int n0 = bj * 128;   // col tile
    const _Float16* __restrict__ Xb = xn + (size_t)blockIdx.y * T_ * D_;
    float* __restrict__ Cb = out + (size_t)blockIdx.y * T_ * T_;

    const int tid  = threadIdx.x;
    const int wave = tid >> 6;
    const int lane = tid & 63;
    const int wrow = (wave >> 1) * 64;
    const int wcol = (wave & 1) * 64;

    const int srow = wave * 32 + (lane >> 2);
    const _Float16* ga = Xb + (size_t)(m0 + srow) * D_ + (lane & 3) * 8;
    const _Float16* gb = Xb + (size_t)(n0 + srow) * D_ + (lane & 3) * 8;
    _Float16* la = ldsA + wave * 1024;
    _Float16* lb = ldsB + wave * 1024;

    const int fr = lane & 15;
    const int fk = (lane >> 4) * 8;

    floatx4 acc[4][4] = {};

    for (int k0 = 0; k0 < D_; k0 += 32) {
        GLOAD_LDS16(ga + k0,           la);
        GLOAD_LDS16(ga + k0 + 16 * D_, la + 512);
        GLOAD_LDS16(gb + k0,           lb);
        GLOAD_LDS16(gb + k0 + 16 * D_, lb + 512);
        __syncthreads();

        half8 af[4], bf[4];
        #pragma unroll
        for (int i = 0; i < 4; ++i) {
            af[i] = *(const half8*)(ldsA + (wrow + i * 16 + fr) * 32 + fk);
            bf[i] = *(const half8*)(ldsB + (wcol + i * 16 + fr) * 32 + fk);
        }
        #pragma unroll
        for (int i = 0; i < 4; ++i)
            #pragma unroll
            for (int j = 0; j < 4; ++j)
                acc[i][j] = __builtin_amdgcn_mfma_f32_16x16x32_f16(
                    af[i], bf[j], acc[i][j], 0, 0, 0);
        __syncthreads();
    }

    // ---- normal tile: C/D layout col=lane&15, row=(lane>>4)*4+reg ----
    // row within quadrant: q4 = (lane>>4)*4 + r ; col within quadrant: c16 = lane&15
    const int crow = m0 + wrow + (lane >> 4) * 4;   // + i*16 + r
    const int ccol = n0 + wcol + (lane & 15);       // + j*16
    #pragma unroll
    for (int i = 0; i < 4; ++i)
        #pragma unroll
        for (int j = 0; j < 4; ++j)
            #pragma unroll
            for (int r = 0; r < 4; ++r)
                Cb[(size_t)(crow + i * 16 + r) * T_ + (ccol + j * 16)] = acc[i][j][r];

    if (bi == bj) return;   // block-uniform; diagonal done

    // ---- mirror tile: same values, swapped indexing, straight from acc ----
    // C(n0+col, m0+row) = acc value at (row, col). Scattered 4B stores; the
    // block fully covers every 64B line of the mirror tile, so L2 write-back
    // emits full lines and HBM write traffic is unchanged.
    const int mrow = n0 + wcol + (lane & 15);       // + j*16   (mirror row = orig col)
    const int mcol = m0 + wrow + (lane >> 4) * 4;   // + i*16 + r (mirror col = orig row)
    #pragma unroll
    for (int j = 0; j < 4; ++j)
        #pragma unroll
        for (int i = 0; i < 4; ++i)
            #pragma unroll
            for (int r = 0; r < 4; ++r)
                Cb[(size_t)(mrow + j * 16) * T_ + (mcol + i * 16 + r)] = acc[i][j][r];
}

extern "C" void kernel_launch(void* const* d_in, const int* in_sizes, int n_in,
                              void* d_out, int out_size, void* d_ws, size_t ws_size,
                              hipStream_t stream) {
    const float* x = (const float*)d_in[0];
    float* out = (float*)d_out;
    _Float16* xn = (_Float16*)d_ws;   // 8*2048*512 f16 = 16.8 MB

    normalize_f16<<<dim3(B_ * T_ / 4), dim3(256), 0, stream>>>(x, xn);
    ssm_gemm<<<dim3(136, B_), dim3(256), 0, stream>>>(xn, out);
}